// Round 7
// baseline (74.443 us; speedup 1.0000x reference)
//
#include <hip/hip_runtime.h>
#include <hip/hip_bf16.h>

// Grouped linear: concat(x0..x3) rows [M=294912, K=128] @ W^T[128,128] + bias -> fp32 out.
// bf16 MFMA 32x32x16 (2x FLOPs per instruction vs 16x16x32 at same operand width).
// 768 blocks x 256 threads (zero tail); block = 384 rows; wave-tile = 32 rows, 3 tiles/wave,
// 2-deep pipeline. W staged once per block in swizzled LDS; x direct global->reg.

typedef __attribute__((ext_vector_type(8)))  short bf8_t;   // 8 x bf16 (4 VGPRs) = A/B operand
typedef __attribute__((ext_vector_type(4)))  float f4_t;
typedef __attribute__((ext_vector_type(16))) float f16_t;   // 32x32 accumulator

__device__ __forceinline__ short bfc(float f) {
    // compiler pairs these into v_cvt_pk_bf16_f32 (RNE)
    return __builtin_bit_cast(short, __float2bfloat16(f));
}

__device__ __forceinline__ unsigned short f2bf_rne(float f) {
    unsigned u = __builtin_bit_cast(unsigned, f);
    u += 0x7fffu + ((u >> 16) & 1u);
    return (unsigned short)(u >> 16);
}

#define SEG0 131072L   // rows in x0 (32*64*64)
#define SEG1 196608L   // + x1 (32*32*64)
#define SEG2 262144L   // + x2 (32*64*32)
// boundaries are multiples of 65536 -> any 32-aligned 32-row group is single-segment.

__device__ __forceinline__ void resolve(long gr,
    const float* __restrict__ x0, const float* __restrict__ x1,
    const float* __restrict__ x2, const float* __restrict__ x3,
    float* __restrict__ out, const float** xr, float** orow)
{
    const float* xp; long loc;
    if      (gr < SEG0) { xp = x0; loc = gr; }
    else if (gr < SEG1) { xp = x1; loc = gr - SEG0; }
    else if (gr < SEG2) { xp = x2; loc = gr - SEG1; }
    else                { xp = x3; loc = gr - SEG2; }
    *xr   = xp + loc * 128;
    *orow = out + gr * 128;
}

__device__ __forceinline__ void load_tile(f4_t (&raw)[16], const float* __restrict__ xrow, int hi)
{
    // lane reads x[row = lane&31][k = ks*16 + hi*8 + j], j=0..7  (two dwordx4 per ks)
#pragma unroll
    for (int ks = 0; ks < 8; ++ks) {
        const float* p = xrow + ks * 16 + hi * 8;
        raw[2 * ks]     = *reinterpret_cast<const f4_t*>(p);
        raw[2 * ks + 1] = *reinterpret_cast<const f4_t*>(p + 4);
    }
}

__device__ __forceinline__ void compute_store(
    const f4_t (&raw)[16], const unsigned short* __restrict__ Wl,
    const float* __restrict__ bl, float* __restrict__ orow,
    int xm, int hi, int nsw)
{
    // acc[nt] = D tile nt: D[m=feature][n=x-row]; lane holds n=xm, features
    // nt*32 + (reg&3) + 8*(reg>>2) + 4*hi. Init from bias (broadcast LDS reads).
    f16_t acc[4];
#pragma unroll
    for (int nt = 0; nt < 4; ++nt) {
#pragma unroll
        for (int q = 0; q < 4; ++q) {
            f4_t b4 = *reinterpret_cast<const f4_t*>(&bl[nt * 32 + q * 8 + hi * 4]);
            acc[nt][4 * q + 0] = b4.x;
            acc[nt][4 * q + 1] = b4.y;
            acc[nt][4 * q + 2] = b4.z;
            acc[nt][4 * q + 3] = b4.w;
        }
    }

#pragma unroll
    for (int ks = 0; ks < 8; ++ks) {
        // B-fragment: 8 bf16 of this lane's x row, k = ks*16 + hi*8 + (0..7)
        f4_t a = raw[2 * ks], b = raw[2 * ks + 1];
        bf8_t xf;
        xf[0] = bfc(a.x); xf[1] = bfc(a.y); xf[2] = bfc(a.z); xf[3] = bfc(a.w);
        xf[4] = bfc(b.x); xf[5] = bfc(b.y); xf[6] = bfc(b.z); xf[7] = bfc(b.w);
        const int c = ((2 * ks + hi) ^ nsw) * 8;   // swizzled 16B chunk offset (shorts)
#pragma unroll
        for (int nt = 0; nt < 4; ++nt) {
            const int nrow = nt * 32 + xm;         // W feature row; nrow&7 == xm&7 == nsw-source
            bf8_t wf = *reinterpret_cast<const bf8_t*>(&Wl[nrow * 128 + c]);
            acc[nt] = __builtin_amdgcn_mfma_f32_32x32x16_bf16(wf, xf, acc[nt], 0, 0, 0);
        }
    }

    // stores: lane writes 4x f4 per nt (16B contiguous), full row covered by the wave
#pragma unroll
    for (int nt = 0; nt < 4; ++nt) {
#pragma unroll
        for (int q = 0; q < 4; ++q) {
            f4_t v;
            v.x = acc[nt][4 * q + 0];
            v.y = acc[nt][4 * q + 1];
            v.z = acc[nt][4 * q + 2];
            v.w = acc[nt][4 * q + 3];
            *reinterpret_cast<f4_t*>(orow + nt * 32 + q * 8 + hi * 4) = v;
        }
    }
}

__global__ __launch_bounds__(256)
void lin_kernel(const float* __restrict__ x0, const float* __restrict__ x1,
                const float* __restrict__ x2, const float* __restrict__ x3,
                const float* __restrict__ W, const float* __restrict__ bias,
                float* __restrict__ out)
{
    __shared__ unsigned short Wl[128 * 128]; // bf16 W, 256B rows, 16B-chunk XOR swizzle
    __shared__ float bl[128];

    const int tid = threadIdx.x;

    // ---- stage W: fp32 -> bf16, swizzled (chunk ^= row&7) ----
#pragma unroll
    for (int i = 0; i < 16; ++i) {
        int f  = i * 256 + tid;       // float4 index in W, 0..4095
        int n  = f >> 5;              // W row (output feature)
        int k4 = f & 31;              // float4 index within row
        f4_t v = reinterpret_cast<const f4_t*>(W)[f];
        unsigned long long p =
              (unsigned long long)f2bf_rne(v.x)
            | ((unsigned long long)f2bf_rne(v.y) << 16)
            | ((unsigned long long)f2bf_rne(v.z) << 32)
            | ((unsigned long long)f2bf_rne(v.w) << 48);
        int sc = (k4 >> 1) ^ (n & 7); // swizzled 16B-chunk index
        *reinterpret_cast<unsigned long long*>(&Wl[n * 128 + sc * 8 + (k4 & 1) * 4]) = p;
    }
    if (tid < 128) bl[tid] = bias[tid];
    __syncthreads();

    const int wave = tid >> 6;
    const int lane = tid & 63;
    const int xm   = lane & 31;   // x row within 32-row wave-tile
    const int hi   = lane >> 5;   // k-subgroup (0/1)
    const int nsw  = lane & 7;    // W-read swizzle key (== nrow&7)

    // block owns rows [blockIdx*384, +384); block-tile = 128 rows (4 waves x 32); 3 tiles.
    const long r0 = (long)blockIdx.x * 384 + wave * 32 + xm;

    // ---- 2-deep pipeline over 3 tiles ----
    f4_t rawA[16], rawB[16];
    const float* xA; const float* xB;
    float* oA; float* oB;

    resolve(r0 +   0, x0, x1, x2, x3, out, &xA, &oA); load_tile(rawA, xA, hi);
    resolve(r0 + 128, x0, x1, x2, x3, out, &xB, &oB); load_tile(rawB, xB, hi);
    compute_store(rawA, Wl, bl, oA, xm, hi, nsw);
    resolve(r0 + 256, x0, x1, x2, x3, out, &xA, &oA); load_tile(rawA, xA, hi);
    compute_store(rawB, Wl, bl, oB, xm, hi, nsw);
    compute_store(rawA, Wl, bl, oA, xm, hi, nsw);
}

extern "C" void kernel_launch(void* const* d_in, const int* in_sizes, int n_in,
                              void* d_out, int out_size, void* d_ws, size_t ws_size,
                              hipStream_t stream) {
    const float* x0 = (const float*)d_in[0];
    const float* x1 = (const float*)d_in[1];
    const float* x2 = (const float*)d_in[2];
    const float* x3 = (const float*)d_in[3];
    const float* W  = (const float*)d_in[4];
    const float* b  = (const float*)d_in[5];
    float* out = (float*)d_out;

    // 294912 rows / 384 rows per block = 768 blocks (zero tail)
    hipLaunchKernelGGL(lin_kernel, dim3(768), dim3(256), 0, stream,
                       x0, x1, x2, x3, W, b, out);
}

// Round 8
// 65.808 us; speedup vs baseline: 1.1312x; 1.1312x over previous
//
#include <hip/hip_runtime.h>
#include <hip/hip_bf16.h>

// Grouped linear: concat(x0..x3) rows [M=294912, K=128] @ W^T[128,128] + bias -> fp32 out.
// Structure (R8): W held in REGISTERS per wave (32-feature strip, loaded once);
// x staged global->LDS via global_load_lds width=16 (zero-VGPR staging, both-sides XOR
// swizzle), double-buffered 64-row tiles; 2-phase pipeline (stage t+1 || compute t).
// 512 blocks x 256 threads = exactly 2 resident blocks/CU (64 KB LDS each), zero tail.

typedef __attribute__((ext_vector_type(8))) short bf8_t;   // 8 x bf16 (4 VGPRs)
typedef __attribute__((ext_vector_type(4))) float f4_t;

typedef const unsigned __attribute__((address_space(1)))* gp_t;
typedef unsigned __attribute__((address_space(3)))* lp_t;

__device__ __forceinline__ short bfc(float f) {
    // compiler pairs these into v_cvt_pk_bf16_f32 (RNE)
    return __builtin_bit_cast(short, __float2bfloat16(f));
}

#define SEG0 131072L   // rows in x0 (32*64*64)
#define SEG1 196608L   // + x1 (32*32*64)
#define SEG2 262144L   // + x2 (32*64*32)
// boundaries are multiples of 64 -> every 64-row tile is single-segment.

__device__ __forceinline__ const float* tile_src(long gr,
    const float* __restrict__ x0, const float* __restrict__ x1,
    const float* __restrict__ x2, const float* __restrict__ x3)
{
    const float* xp; long loc;
    if      (gr < SEG0) { xp = x0; loc = gr; }
    else if (gr < SEG1) { xp = x1; loc = gr - SEG0; }
    else if (gr < SEG2) { xp = x2; loc = gr - SEG1; }
    else                { xp = x3; loc = gr - SEG2; }
    return xp + loc * 128;
}

// Stage one 64x128 fp32 tile (32 KB) into LDS. LDS dest is linear (wave-uniform base +
// lane*16 by HW); the XOR swizzle is applied on the GLOBAL SOURCE side (rule #21):
// LDS chunk (r, kc) holds global chunk (r, kc ^ (r&7)) -- an involution.
__device__ __forceinline__ void stage_tile(const float* __restrict__ src,
                                           float* __restrict__ buf,
                                           int wave, int lane)
{
#pragma unroll
    for (int i = 0; i < 8; ++i) {
        const int c  = i * 256 + wave * 64 + lane;   // 16B-chunk index 0..2047
        const int r  = c >> 5;                       // row 0..63
        const int kc = c & 31;                       // chunk within row
        const float* g = src + r * 128 + ((kc ^ (r & 7)) << 2);
        float* l = buf + (i * 256 + wave * 64) * 4;  // wave-uniform; +lane*16B implicit
        __builtin_amdgcn_global_load_lds((gp_t)g, (lp_t)l, 16, 0, 0);
    }
}

// Compute 64 rows x this wave's 32 features from the staged tile.
__device__ __forceinline__ void compute_tile(const float* __restrict__ buf,
    float* __restrict__ obase, const bf8_t (&wf)[2][4],
    f4_t bf0, f4_t bf1, int wave, int lm, int lk)
{
#pragma unroll
    for (int s = 0; s < 4; ++s) {
        const int row = s * 16 + lm;
        const int sw  = row & 7;
        // lane reads x[row][k = ks*32 + lk*8 + (0..7)] = swizzled chunks ks*8+lk*2+{0,1}
        f4_t raw[8];
#pragma unroll
        for (int ks = 0; ks < 4; ++ks) {
            const int c0 = ks * 8 + lk * 2;
            raw[2*ks]   = *reinterpret_cast<const f4_t*>(buf + row * 128 + (((c0    ) ^ sw) << 2));
            raw[2*ks+1] = *reinterpret_cast<const f4_t*>(buf + row * 128 + (((c0 + 1) ^ sw) << 2));
        }
        bf8_t xf[4];
#pragma unroll
        for (int ks = 0; ks < 4; ++ks) {
            f4_t a = raw[2*ks], b = raw[2*ks+1];
            bf8_t t;
            t[0]=bfc(a.x); t[1]=bfc(a.y); t[2]=bfc(a.z); t[3]=bfc(a.w);
            t[4]=bfc(b.x); t[5]=bfc(b.y); t[6]=bfc(b.z); t[7]=bfc(b.w);
            xf[ks] = t;
        }
        // D: col = lane&15 = x-row, feature = wave*32 + nt*16 + lk*4 + j
        f4_t acc0 = bf0, acc1 = bf1;
#pragma unroll
        for (int ks = 0; ks < 4; ++ks) {
            acc0 = __builtin_amdgcn_mfma_f32_16x16x32_bf16(wf[0][ks], xf[ks], acc0, 0, 0, 0);
            acc1 = __builtin_amdgcn_mfma_f32_16x16x32_bf16(wf[1][ks], xf[ks], acc1, 0, 0, 0);
        }
        float* orow = obase + (long)row * 128 + wave * 32 + lk * 4;
        __builtin_nontemporal_store(acc0, reinterpret_cast<f4_t*>(orow));
        __builtin_nontemporal_store(acc1, reinterpret_cast<f4_t*>(orow + 16));
    }
}

__global__ __launch_bounds__(256)
void lin_kernel(const float* __restrict__ x0, const float* __restrict__ x1,
                const float* __restrict__ x2, const float* __restrict__ x3,
                const float* __restrict__ W, const float* __restrict__ bias,
                float* __restrict__ out)
{
    __shared__ float xb0[64 * 128];   // 32 KB
    __shared__ float xb1[64 * 128];   // 32 KB

    const int tid  = threadIdx.x;
    const int wave = tid >> 6;
    const int lane = tid & 63;
    const int lm   = lane & 15;   // x-row within 16 / W-feature row within 16
    const int lk   = lane >> 4;   // k-subgroup 0..3

    const long blk0 = (long)blockIdx.x * 576;   // block owns 9 tiles of 64 rows

    // ---- prologue: start staging tile 0 immediately ----
    stage_tile(tile_src(blk0, x0, x1, x2, x3), xb0, wave, lane);

    // ---- W fragments in registers (once per kernel): wave owns features [wave*32,+32) ----
    bf8_t wf[2][4];
#pragma unroll
    for (int nt = 0; nt < 2; ++nt) {
        const int nW = wave * 32 + nt * 16 + lm;
#pragma unroll
        for (int ks = 0; ks < 4; ++ks) {
            const float* p = W + nW * 128 + ks * 32 + lk * 8;
            f4_t a = *reinterpret_cast<const f4_t*>(p);
            f4_t b = *reinterpret_cast<const f4_t*>(p + 4);
            bf8_t t;
            t[0]=bfc(a.x); t[1]=bfc(a.y); t[2]=bfc(a.z); t[3]=bfc(a.w);
            t[4]=bfc(b.x); t[5]=bfc(b.y); t[6]=bfc(b.z); t[7]=bfc(b.w);
            wf[nt][ks] = t;
        }
    }
    // bias fragments: feature = wave*32 + nt*16 + lk*4 + j
    const f4_t bf0 = *reinterpret_cast<const f4_t*>(bias + wave * 32 +      lk * 4);
    const f4_t bf1 = *reinterpret_cast<const f4_t*>(bias + wave * 32 + 16 + lk * 4);

    asm volatile("s_waitcnt vmcnt(0)" ::: "memory");
    __builtin_amdgcn_s_barrier();

    // ---- 2-phase main loop over 9 tiles ----
    float* cur = xb0;
    float* nxt = xb1;
#pragma unroll 1
    for (int t = 0; t < 9; ++t) {
        if (t < 8)
            stage_tile(tile_src(blk0 + (t + 1) * 64, x0, x1, x2, x3), nxt, wave, lane);
        compute_tile(cur, out + (blk0 + t * 64) * 128, wf, bf0, bf1, wave, lm, lk);
        if (t < 8) {
            asm volatile("s_waitcnt vmcnt(0)" ::: "memory");
            __builtin_amdgcn_s_barrier();
        }
        float* tmp = cur; cur = nxt; nxt = tmp;
    }
}

extern "C" void kernel_launch(void* const* d_in, const int* in_sizes, int n_in,
                              void* d_out, int out_size, void* d_ws, size_t ws_size,
                              hipStream_t stream) {
    const float* x0 = (const float*)d_in[0];
    const float* x1 = (const float*)d_in[1];
    const float* x2 = (const float*)d_in[2];
    const float* x3 = (const float*)d_in[3];
    const float* W  = (const float*)d_in[4];
    const float* b  = (const float*)d_in[5];
    float* out = (float*)d_out;

    // 294912 rows / 576 rows per block = 512 blocks = exactly 2 resident per CU
    hipLaunchKernelGGL(lin_kernel, dim3(512), dim3(256), 0, stream,
                       x0, x1, x2, x3, W, b, out);
}